// Round 2
// baseline (875.464 us; speedup 1.0000x reference)
//
#include <hip/hip_runtime.h>
#include <hip/hip_bf16.h>
#include <math.h>

#define C_DIM 256
#define H_HEADS 8
#define B_GRAPHS 2048
#define NPG 128
#define N_NODES (B_GRAPHS * NPG)   // 262144
#define EPS 1e-5f
#define SCALE_ATT 0.17677669529663687f   // 1/sqrt(32)
#define GEMM_BLOCKS 4096                 // 64 nodes per block

typedef short bf16x8 __attribute__((ext_vector_type(8)));
typedef float f32x4 __attribute__((ext_vector_type(4)));

__device__ __forceinline__ unsigned short f2bf(float f) {
    __hip_bfloat16 h = __float2bfloat16(f);
    union { __hip_bfloat16 h; unsigned short u; } cv; cv.h = h; return cv.u;
}
__device__ __forceinline__ float bf2f(unsigned short u) {
    union { unsigned int i; float f; } v; v.i = ((unsigned int)u) << 16; return v.f;
}

// ---------------- GEMM (blocks 0..4095) + per-head fold (blocks 4096..4103) ----------------
// GEMM: h1[n][c] = sum_k x[n,k]*W1[c,k]  (b1 cancels through batch-LN).
// LDS-FREE: every 16B MFMA fragment is consumed by exactly one lane (waves own
// disjoint 64-channel ranges; the 4 waves' shared x slice lives in L1), so
// operands load global->reg directly. No __syncthreads in the GEMM path.
// Wave w: channels [w*64,(w+1)*64), 4 node-subtiles in-thread -> stats reduce is
// 8-value in-register + 4-level shfl (128 shfls/thread, was 512), channels
// wave-disjoint -> direct global atomicAdd.
__global__ __launch_bounds__(256, 3) void gemm_kernel(
    const float* __restrict__ x, const float* __restrict__ W1,
    unsigned short* __restrict__ h1,
    float* __restrict__ psum, float* __restrict__ psum2,
    const float* __restrict__ W2, const float* __restrict__ Wv,
    const float* __restrict__ b2, const float* __restrict__ bv,
    const float* __restrict__ bo,
    const float* __restrict__ Wq, const float* __restrict__ bq,
    const float* __restrict__ Wk, const float* __restrict__ Wo,
    const float* __restrict__ Wr, const float* __restrict__ br,
    unsigned short* __restrict__ WBg, float* __restrict__ c0)
{
    const int t = threadIdx.x;

    if (blockIdx.x >= GEMM_BLOCKS) {
        // ---- self-contained per-head fold (no prep dependency) ----
        __shared__ float qhS[256];
        __shared__ float wkS[256];
        __shared__ float vS[256];
        __shared__ float worP[8][32];
        __shared__ float worS[32];
        const int head = blockIdx.x - GEMM_BLOCKS;
        {   // qh[c] = bq[c] + rowsum(Wq[c,:])
            float s = bq[t];
            const float* row = Wq + (size_t)t * 256;
            for (int c = 0; c < 256; c += 4) {
                float4 v = *(const float4*)&row[c];
                s += v.x + v.y + v.z + v.w;
            }
            qhS[t] = s;
        }
        {   // wor[head*32+jj] = sum_j2 Wo[j2, head*32+jj] * Wr[j2]
            int jj = t & 31, grp = t >> 5;
            float acc = 0.f;
            #pragma unroll 4
            for (int m = 0; m < 32; ++m) {
                int j2 = grp * 32 + m;
                acc = fmaf(Wo[(size_t)j2 * 256 + head * 32 + jj], Wr[j2], acc);
            }
            worP[grp][jj] = acc;
        }
        __syncthreads();
        if (t < 32) {
            float s = 0.f;
            #pragma unroll
            for (int g2 = 0; g2 < 8; ++g2) s += worP[g2][t];
            worS[t] = s;
        }
        {   // wk_h[c'] = scale * sum_d Wk[head*32+d, c'] * qh[head*32+d]
            float acc = 0.f;
            #pragma unroll 4
            for (int d = 0; d < 32; ++d)
                acc = fmaf(Wk[(size_t)(head * 32 + d) * 256 + t], qhS[head * 32 + d], acc);
            wkS[t] = acc * SCALE_ATT;
        }
        __syncthreads();
        {   // wfold row (logits weights)
            float acc = 0.f;
            #pragma unroll 4
            for (int cp = 0; cp < 256; ++cp)
                acc = fmaf(W2[(size_t)cp * 256 + t], wkS[cp], acc);
            WBg[head * 256 + t] = f2bf(acc);
        }
        float accv = 0.f;   // V_h[c] = sum_d Wv[head*32+d, c] * wor[head*32+d]
        #pragma unroll 4
        for (int d = 0; d < 32; ++d)
            accv = fmaf(Wv[(size_t)(head * 32 + d) * 256 + t], worS[d], accv);
        vS[t] = accv;
        __syncthreads();
        {   // G row (gdot weights)
            float acc = 0.f;
            #pragma unroll 4
            for (int cp = 0; cp < 256; ++cp)
                acc = fmaf(W2[(size_t)cp * 256 + t], vS[cp], acc);
            WBg[(8 + head) * 256 + t] = f2bf(acc);
        }
        // c0 partials: b2.V_h (full) + bv.wor (this head's 32 j) + head0: bo.Wr + br
        float part = b2[t] * accv;
        if (t < 32) part += bv[head * 32 + t] * worS[t];
        if (head == 0) {
            part += bo[t] * Wr[t];
            if (t == 0) part += br[0];
        }
        #pragma unroll
        for (int s = 1; s < 64; s <<= 1) part += __shfl_xor(part, s);
        if ((t & 63) == 0) atomicAdd(c0, part);
        return;
    }

    const int lane = t & 63, w = t >> 6;
    const int l15 = lane & 15, kg = lane >> 4;
    const size_t n0 = (size_t)blockIdx.x * 64;
    const int wc = w * 64;

    f32x4 acc[4][4];   // [mti][nst]
    #pragma unroll
    for (int mti = 0; mti < 4; ++mti)
        #pragma unroll
        for (int nst = 0; nst < 4; ++nst)
            acc[mti][nst] = (f32x4){0.f, 0.f, 0.f, 0.f};

    #pragma unroll 2
    for (int kk = 0; kk < 8; ++kk) {
        const int ko = kk * 32 + kg * 8;
        bf16x8 af[4];
        #pragma unroll
        for (int mti = 0; mti < 4; ++mti) {
            const float* wp = &W1[(size_t)(wc + mti * 16 + l15) * 256 + ko];
            float4 w0 = *(const float4*)wp;
            float4 w1 = *(const float4*)(wp + 4);
            bf16x8 a;
            a[0] = (short)f2bf(w0.x); a[1] = (short)f2bf(w0.y);
            a[2] = (short)f2bf(w0.z); a[3] = (short)f2bf(w0.w);
            a[4] = (short)f2bf(w1.x); a[5] = (short)f2bf(w1.y);
            a[6] = (short)f2bf(w1.z); a[7] = (short)f2bf(w1.w);
            af[mti] = a;
        }
        #pragma unroll
        for (int nst = 0; nst < 4; ++nst) {
            const float* xp = &x[(n0 + nst * 16 + l15) * 256 + ko];
            float4 x0 = *(const float4*)xp;
            float4 x1 = *(const float4*)(xp + 4);
            bf16x8 b;
            b[0] = (short)f2bf(x0.x); b[1] = (short)f2bf(x0.y);
            b[2] = (short)f2bf(x0.z); b[3] = (short)f2bf(x0.w);
            b[4] = (short)f2bf(x1.x); b[5] = (short)f2bf(x1.y);
            b[6] = (short)f2bf(x1.z); b[7] = (short)f2bf(x1.w);
            #pragma unroll
            for (int mti = 0; mti < 4; ++mti)
                acc[mti][nst] = __builtin_amdgcn_mfma_f32_16x16x32_bf16(af[mti], b, acc[mti][nst], 0, 0, 0);
        }
    }

    // ---- epilogue: row-major packed stores ----
    #pragma unroll
    for (int nst = 0; nst < 4; ++nst) {
        const size_t rowb = (n0 + nst * 16 + l15) * 256 + wc + kg * 4;
        #pragma unroll
        for (int mti = 0; mti < 4; ++mti) {
            f32x4 a = acc[mti][nst];
            ushort4 u;
            u.x = f2bf(a[0]); u.y = f2bf(a[1]); u.z = f2bf(a[2]); u.w = f2bf(a[3]);
            *(ushort4*)&h1[rowb + mti * 16] = u;
        }
    }

    // ---- stats: in-register nst-sum then 4-level l15 butterfly ----
    float s1[4][4], s2[4][4];
    #pragma unroll
    for (int mti = 0; mti < 4; ++mti)
        #pragma unroll
        for (int r = 0; r < 4; ++r) {
            float a0 = acc[mti][0][r], a1 = acc[mti][1][r];
            float a2 = acc[mti][2][r], a3 = acc[mti][3][r];
            s1[mti][r] = (a0 + a1) + (a2 + a3);
            s2[mti][r] = (a0 * a0 + a1 * a1) + (a2 * a2 + a3 * a3);
        }
    #pragma unroll
    for (int s = 1; s < 16; s <<= 1)
        #pragma unroll
        for (int mti = 0; mti < 4; ++mti)
            #pragma unroll
            for (int r = 0; r < 4; ++r) {
                s1[mti][r] += __shfl_xor(s1[mti][r], s);
                s2[mti][r] += __shfl_xor(s2[mti][r], s);
            }
    if (l15 == 0) {
        #pragma unroll
        for (int mti = 0; mti < 4; ++mti)
            #pragma unroll
            for (int r = 0; r < 4; ++r) {
                int c = wc + mti * 16 + kg * 4 + r;
                atomicAdd(&psum[c], s1[mti][r]);
                atomicAdd(&psum2[c], s2[mti][r]);
            }
    }
}

// ---------------- fused per-graph kernel (LDS-free LN path) ----------------
// A = WB rows (16 j), B = LN+ReLU(h1) node rows, built in registers from row-major h1.
__global__ __launch_bounds__(256) void fused_kernel(
    const unsigned short* __restrict__ h1,
    const float* __restrict__ psum, const float* __restrict__ psum2,
    const float* __restrict__ gamma, const float* __restrict__ beta,
    const unsigned short* __restrict__ WBg,
    const float* __restrict__ c0_g, float* __restrict__ out)
{
    __shared__ float scS[256], shS[256];
    __shared__ float LG[128 * 17];
    __shared__ float redH[8];

    const int t = threadIdx.x;
    const int g = blockIdx.x;
    const int lane = t & 63, w = t >> 6;
    const int l15 = lane & 15, kg = lane >> 4;

    {   // finalize LN stats per block (1 KB L2-resident reads)
        const float invN = 1.0f / (float)N_NODES;
        float S = psum[t], S2 = psum2[t];
        float mu = S * invN;
        float var = S2 * invN - mu * mu;
        float rstd = rsqrtf(var + EPS);
        float gmr = gamma[t] * rstd;
        scS[t] = gmr;
        shS[t] = beta[t] - mu * gmr;
    }
    bf16x8 af[8];
    #pragma unroll
    for (int kt = 0; kt < 8; ++kt)
        af[kt] = *(const bf16x8*)&WBg[l15 * 256 + kt * 32 + kg * 8];
    __syncthreads();

    const size_t base0 = ((size_t)g * 128 + w * 32 + l15) * 256;
    const size_t base1 = base0 + 16 * 256;
    f32x4 acc0 = {0.f, 0.f, 0.f, 0.f}, acc1 = {0.f, 0.f, 0.f, 0.f};
    #pragma unroll
    for (int kt = 0; kt < 8; ++kt) {
        const int cc = kt * 32 + kg * 8;
        bf16x8 h0 = *(const bf16x8*)&h1[base0 + cc];
        bf16x8 h1v = *(const bf16x8*)&h1[base1 + cc];
        f32x4 scA = *(const f32x4*)&scS[cc];
        f32x4 scB = *(const f32x4*)&scS[cc + 4];
        f32x4 shA = *(const f32x4*)&shS[cc];
        f32x4 shB = *(const f32x4*)&shS[cc + 4];
        bf16x8 b0, b1;
        #pragma unroll
        for (int e = 0; e < 4; ++e) {
            b0[e]     = (short)f2bf(fmaxf(fmaf(bf2f((unsigned short)h0[e]),      scA[e], shA[e]), 0.f));
            b0[e + 4] = (short)f2bf(fmaxf(fmaf(bf2f((unsigned short)h0[e + 4]),  scB[e], shB[e]), 0.f));
            b1[e]     = (short)f2bf(fmaxf(fmaf(bf2f((unsigned short)h1v[e]),     scA[e], shA[e]), 0.f));
            b1[e + 4] = (short)f2bf(fmaxf(fmaf(bf2f((unsigned short)h1v[e + 4]), scB[e], shB[e]), 0.f));
        }
        acc0 = __builtin_amdgcn_mfma_f32_16x16x32_bf16(af[kt], b0, acc0, 0, 0, 0);
        acc1 = __builtin_amdgcn_mfma_f32_16x16x32_bf16(af[kt], b1, acc1, 0, 0, 0);
    }
    #pragma unroll
    for (int r = 0; r < 4; ++r) {
        LG[(w * 32 + l15) * 17 + kg * 4 + r]      = acc0[r];
        LG[(w * 32 + 16 + l15) * 17 + kg * 4 + r] = acc1[r];
    }
    __syncthreads();

    {   // per-head softmax-weighted gdot
        const int h = t >> 5, j = t & 31;
        float l[4], gv[4];
        #pragma unroll
        for (int q = 0; q < 4; ++q) {
            int n = j + q * 32;
            l[q]  = LG[n * 17 + h];
            gv[q] = LG[n * 17 + 8 + h];
        }
        float m = fmaxf(fmaxf(l[0], l[1]), fmaxf(l[2], l[3]));
        for (int s = 16; s > 0; s >>= 1) m = fmaxf(m, __shfl_xor(m, s, 32));
        float sp = 0.f, sg = 0.f;
        #pragma unroll
        for (int q = 0; q < 4; ++q) {
            float p = expf(l[q] - m);
            sp += p;
            sg = fmaf(p, gv[q], sg);
        }
        for (int s = 16; s > 0; s >>= 1) {
            sp += __shfl_xor(sp, s, 32);
            sg += __shfl_xor(sg, s, 32);
        }
        if (j == 0) redH[h] = sg / sp;
    }
    __syncthreads();
    if (t == 0) {
        float r = c0_g[0];
        #pragma unroll
        for (int h = 0; h < 8; ++h) r += redH[h];
        out[g] = tanhf(r);
    }
}

// ---------------- launch ----------------
// ws: h1 (N*256 u16) | WBg (4096 u16) | floats: psum[256] | psum2[256] | c0[1]
extern "C" void kernel_launch(void* const* d_in, const int* in_sizes, int n_in,
                              void* d_out, int out_size, void* d_ws, size_t ws_size,
                              hipStream_t stream)
{
    (void)in_sizes; (void)n_in; (void)out_size; (void)ws_size;
    const float* x     = (const float*)d_in[0];
    const float* W1    = (const float*)d_in[3];
    // d_in[4] = b1: cancels exactly through the batch-mean subtraction in LN
    const float* gamma = (const float*)d_in[5];
    const float* beta  = (const float*)d_in[6];
    const float* W2    = (const float*)d_in[7];
    const float* b2    = (const float*)d_in[8];
    const float* Wq    = (const float*)d_in[9];
    const float* bq    = (const float*)d_in[10];
    const float* Wk    = (const float*)d_in[11];
    const float* Wv    = (const float*)d_in[13];
    const float* bv    = (const float*)d_in[14];
    const float* Wo    = (const float*)d_in[15];
    const float* bo    = (const float*)d_in[16];
    const float* Wr    = (const float*)d_in[17];
    const float* br    = (const float*)d_in[18];

    unsigned short* h1  = (unsigned short*)d_ws;
    unsigned short* WBg = h1 + (size_t)N_NODES * 256;
    float* fbase = (float*)(WBg + 4096);

    float* psum  = fbase;
    float* psum2 = fbase + 256;
    float* c0    = fbase + 512;

    hipMemsetAsync((void*)psum, 0, 513 * sizeof(float), stream);

    hipLaunchKernelGGL(gemm_kernel, dim3(GEMM_BLOCKS + 8), dim3(256), 0, stream,
                       x, W1, h1, psum, psum2,
                       W2, Wv, b2, bv, bo, Wq, bq, Wk, Wo, Wr, br, WBg, c0);
    hipLaunchKernelGGL(fused_kernel, dim3(B_GRAPHS), dim3(256), 0, stream,
                       h1, psum, psum2, gamma, beta, WBg, c0, (float*)d_out);
}

// Round 3
// 518.643 us; speedup vs baseline: 1.6880x; 1.6880x over previous
//
#include <hip/hip_runtime.h>
#include <hip/hip_bf16.h>
#include <math.h>

#define B_GRAPHS 2048
#define NPG 128
#define N_NODES (B_GRAPHS * NPG)   // 262144
#define EPS 1e-5f
#define SCALE_ATT 0.17677669529663687f   // 1/sqrt(32)
#define NFOLD 8
#define GEMM_BLOCKS 512
#define NODES_PER_BLOCK 512
#define TILES_PER_BLOCK 16               // 32 nodes / tile, 32 KB fp32

typedef short bf16x8 __attribute__((ext_vector_type(8)));
typedef float f32x4 __attribute__((ext_vector_type(4)));

__device__ __forceinline__ unsigned short f2bf(float f) {
    __hip_bfloat16 h = __float2bfloat16(f);
    union { __hip_bfloat16 h; unsigned short u; } cv; cv.h = h; return cv.u;
}
__device__ __forceinline__ float bf2f(unsigned short u) {
    union { unsigned int i; float f; } v; v.i = ((unsigned int)u) << 16; return v.f;
}

// async global->LDS DMA of PIECES*4KB, linear LDS dest, source pre-swizzled:
// swz(o) = o ^ (((o>>SHIFT)&7)<<4)  (involution; SHIFT = log2(row bytes)).
// Readers apply the same XOR -> stride-2^SHIFT row reads spread across banks.
template<int PIECES, int SHIFT>
__device__ __forceinline__ void stage_dma(const char* gsrc, char* ldst, int t)
{
    #pragma unroll
    for (int p = 0; p < PIECES; ++p) {
        unsigned int o = (unsigned int)(p * 256 + t) * 16u;
        unsigned int s = o ^ (((o >> SHIFT) & 7u) << 4);
        __builtin_amdgcn_global_load_lds(
            (const __attribute__((address_space(1))) unsigned int*)(const void*)(gsrc + s),
            (__attribute__((address_space(3))) unsigned int*)(void*)(ldst + o),
            16, 0, 0);
    }
}

// ---------------- fold (blocks 0..7) + GEMM (blocks 8..519) ----------------
// GEMM: h1[n][c] = sum_k x[n,k]*W1[c,k]  (b1 cancels through batch-LN).
// W1 slice persistent in regs (af[4][8] = 128 VGPR / lane, wave w owns 64 ch).
// x staged 32-node tiles via global_load_lds (deep HBM pipeline, counted vmcnt).
// Stats accumulated in regs across all chunks; one butterfly + atomics at end.
__global__ __launch_bounds__(256, 2) void gemm_kernel(
    const float* __restrict__ x, const float* __restrict__ W1,
    unsigned short* __restrict__ h1,
    float* __restrict__ psum, float* __restrict__ psum2,
    const float* __restrict__ W2, const float* __restrict__ Wv,
    const float* __restrict__ b2, const float* __restrict__ bv,
    const float* __restrict__ bo,
    const float* __restrict__ Wq, const float* __restrict__ bq,
    const float* __restrict__ Wk, const float* __restrict__ Wo,
    const float* __restrict__ Wr, const float* __restrict__ br,
    unsigned short* __restrict__ WBg, float* __restrict__ c0)
{
    __shared__ __attribute__((aligned(16))) char xbuf[65536];   // 2 x 32KB fp32 tiles
    __shared__ float qhS[256];
    __shared__ float wkS[256];
    __shared__ float vS[256];
    __shared__ float worP[8][32];
    __shared__ float worS[32];
    const int t = threadIdx.x;

    if (blockIdx.x < NFOLD) {
        // ---- self-contained per-head fold (verbatim from passing version) ----
        const int head = blockIdx.x;
        {   // qh[c] = bq[c] + rowsum(Wq[c,:])
            float s = bq[t];
            const float* row = Wq + (size_t)t * 256;
            for (int c = 0; c < 256; c += 4) {
                float4 v = *(const float4*)&row[c];
                s += v.x + v.y + v.z + v.w;
            }
            qhS[t] = s;
        }
        {   // wor[head*32+jj] = sum_j2 Wo[j2, head*32+jj] * Wr[j2]
            int jj = t & 31, grp = t >> 5;
            float acc = 0.f;
            #pragma unroll 4
            for (int m = 0; m < 32; ++m) {
                int j2 = grp * 32 + m;
                acc = fmaf(Wo[(size_t)j2 * 256 + head * 32 + jj], Wr[j2], acc);
            }
            worP[grp][jj] = acc;
        }
        __syncthreads();
        if (t < 32) {
            float s = 0.f;
            #pragma unroll
            for (int g2 = 0; g2 < 8; ++g2) s += worP[g2][t];
            worS[t] = s;
        }
        {   // wk_h[c'] = scale * sum_d Wk[head*32+d, c'] * qh[head*32+d]
            float acc = 0.f;
            #pragma unroll 4
            for (int d = 0; d < 32; ++d)
                acc = fmaf(Wk[(size_t)(head * 32 + d) * 256 + t], qhS[head * 32 + d], acc);
            wkS[t] = acc * SCALE_ATT;
        }
        __syncthreads();
        {   // wfold row (logits weights)
            float acc = 0.f;
            #pragma unroll 4
            for (int cp = 0; cp < 256; ++cp)
                acc = fmaf(W2[(size_t)cp * 256 + t], wkS[cp], acc);
            WBg[head * 256 + t] = f2bf(acc);
        }
        float accv = 0.f;   // V_h[c] = sum_d Wv[head*32+d, c] * wor[head*32+d]
        #pragma unroll 4
        for (int d = 0; d < 32; ++d)
            accv = fmaf(Wv[(size_t)(head * 32 + d) * 256 + t], worS[d], accv);
        vS[t] = accv;
        __syncthreads();
        {   // G row (gdot weights)
            float acc = 0.f;
            #pragma unroll 4
            for (int cp = 0; cp < 256; ++cp)
                acc = fmaf(W2[(size_t)cp * 256 + t], vS[cp], acc);
            WBg[(8 + head) * 256 + t] = f2bf(acc);
        }
        float part = b2[t] * accv;
        if (t < 32) part += bv[head * 32 + t] * worS[t];
        if (head == 0) {
            part += bo[t] * Wr[t];
            if (t == 0) part += br[0];
        }
        #pragma unroll
        for (int s = 1; s < 64; s <<= 1) part += __shfl_xor(part, s);
        if ((t & 63) == 0) atomicAdd(c0, part);
        return;
    }

    // ---------------- GEMM path ----------------
    const int lane = t & 63, w = t >> 6;
    const int l15 = lane & 15, kg = lane >> 4;
    const int wc = w * 64;
    const size_t n0 = (size_t)(blockIdx.x - NFOLD) * NODES_PER_BLOCK;

    // persistent W1 slice -> registers (read from L2; once per block)
    bf16x8 af[4][8];
    #pragma unroll
    for (int mti = 0; mti < 4; ++mti)
        #pragma unroll
        for (int kk = 0; kk < 8; ++kk) {
            const float* wp = &W1[(size_t)(wc + mti * 16 + l15) * 256 + kk * 32 + kg * 8];
            float4 a0 = *(const float4*)wp;
            float4 a1 = *(const float4*)(wp + 4);
            bf16x8 a;
            a[0] = (short)f2bf(a0.x); a[1] = (short)f2bf(a0.y);
            a[2] = (short)f2bf(a0.z); a[3] = (short)f2bf(a0.w);
            a[4] = (short)f2bf(a1.x); a[5] = (short)f2bf(a1.y);
            a[6] = (short)f2bf(a1.z); a[7] = (short)f2bf(a1.w);
            af[mti][kk] = a;
        }

    float s1[16], s2[16];
    #pragma unroll
    for (int i = 0; i < 16; ++i) { s1[i] = 0.f; s2[i] = 0.f; }

    const char* xg = (const char*)(x + n0 * 256);
    const int e0 = ((kg * 2)     ^ (l15 & 7)) << 4;
    const int e1 = ((kg * 2 + 1) ^ (l15 & 7)) << 4;

    stage_dma<8, 10>(xg, xbuf, t);   // tile 0 -> buf 0

    for (int tile = 0; tile < TILES_PER_BLOCK; ++tile) {
        if (tile + 1 < TILES_PER_BLOCK)
            stage_dma<8, 10>(xg + (size_t)(tile + 1) * 32768,
                             xbuf + ((tile + 1) & 1) * 32768, t);
        // counted waits: 8 = next-tile loads only (tile 0); 16 = 8 prev-tile
        // h1 stores + 8 next-tile loads (in-order vmcnt retirement guarantees
        // the current tile's loads are done); 0 = drain for last tile.
        if (tile == 0)
            asm volatile("s_waitcnt vmcnt(8)\n\ts_barrier" ::: "memory");
        else if (tile + 1 < TILES_PER_BLOCK)
            asm volatile("s_waitcnt vmcnt(16)\n\ts_barrier" ::: "memory");
        else
            asm volatile("s_waitcnt vmcnt(0)\n\ts_barrier" ::: "memory");

        const char* xb = xbuf + (tile & 1) * 32768;
        #pragma unroll
        for (int nst = 0; nst < 2; ++nst) {
            const int node = nst * 16 + l15;
            const int rb = node * 1024;
            f32x4 acc[4];
            #pragma unroll
            for (int mti = 0; mti < 4; ++mti) acc[mti] = (f32x4){0.f, 0.f, 0.f, 0.f};
            #pragma unroll
            for (int kk = 0; kk < 8; ++kk) {
                float4 lo = *(const float4*)(const void*)(xb + rb + kk * 128 + e0);
                float4 hi = *(const float4*)(const void*)(xb + rb + kk * 128 + e1);
                bf16x8 b;
                b[0] = (short)f2bf(lo.x); b[1] = (short)f2bf(lo.y);
                b[2] = (short)f2bf(lo.z); b[3] = (short)f2bf(lo.w);
                b[4] = (short)f2bf(hi.x); b[5] = (short)f2bf(hi.y);
                b[6] = (short)f2bf(hi.z); b[7] = (short)f2bf(hi.w);
                #pragma unroll
                for (int mti = 0; mti < 4; ++mti)
                    acc[mti] = __builtin_amdgcn_mfma_f32_16x16x32_bf16(af[mti][kk], b, acc[mti], 0, 0, 0);
            }
            const size_t rowb = (n0 + (size_t)tile * 32 + node) * 256 + wc + kg * 4;
            #pragma unroll
            for (int mti = 0; mti < 4; ++mti) {
                f32x4 a = acc[mti];
                ushort4 u;
                u.x = f2bf(a[0]); u.y = f2bf(a[1]); u.z = f2bf(a[2]); u.w = f2bf(a[3]);
                *(ushort4*)&h1[rowb + mti * 16] = u;
                #pragma unroll
                for (int r = 0; r < 4; ++r) {
                    s1[mti * 4 + r] += a[r];
                    s2[mti * 4 + r] += a[r] * a[r];
                }
            }
        }
        asm volatile("s_barrier" ::: "memory");   // WAR: buf reused at tile+2
    }

    // stats: one butterfly over l15 at kernel end, then wave-disjoint atomics
    #pragma unroll
    for (int s = 1; s < 16; s <<= 1)
        #pragma unroll
        for (int i = 0; i < 16; ++i) {
            s1[i] += __shfl_xor(s1[i], s);
            s2[i] += __shfl_xor(s2[i], s);
        }
    if (l15 == 0) {
        #pragma unroll
        for (int i = 0; i < 16; ++i) {
            int c = wc + (i >> 2) * 16 + kg * 4 + (i & 3);
            atomicAdd(&psum[c], s1[i]);
            atomicAdd(&psum2[c], s2[i]);
        }
    }
}

// ---------------- fused per-graph kernel (DMA-staged h1) ----------------
// Stage the graph's 64KB h1 tile via global_load_lds (swizzled source), then
// LN+ReLU in regs -> MFMA vs WB (16 j) -> per-head softmax-weighted gdot.
__global__ __launch_bounds__(256) void fused_kernel(
    const unsigned short* __restrict__ h1,
    const float* __restrict__ psum, const float* __restrict__ psum2,
    const float* __restrict__ gamma, const float* __restrict__ beta,
    const unsigned short* __restrict__ WBg,
    const float* __restrict__ c0_g, float* __restrict__ out)
{
    __shared__ __attribute__((aligned(16))) char hbuf[65536];
    __shared__ float scS[256], shS[256];
    __shared__ float LG[128 * 17];
    __shared__ float redH[8];

    const int t = threadIdx.x;
    const int g = blockIdx.x;
    const int lane = t & 63, w = t >> 6;
    const int l15 = lane & 15, kg = lane >> 4;

    stage_dma<16, 9>((const char*)(h1 + (size_t)g * 32768), hbuf, t);

    {   // finalize LN stats per block (1 KB L2-resident reads)
        const float invN = 1.0f / (float)N_NODES;
        float S = psum[t], S2 = psum2[t];
        float mu = S * invN;
        float var = S2 * invN - mu * mu;
        float rstd = rsqrtf(var + EPS);
        float gmr = gamma[t] * rstd;
        scS[t] = gmr;
        shS[t] = beta[t] - mu * gmr;
    }
    bf16x8 af[8];
    #pragma unroll
    for (int kt = 0; kt < 8; ++kt)
        af[kt] = *(const bf16x8*)&WBg[l15 * 256 + kt * 32 + kg * 8];
    __syncthreads();   // implicit vmcnt(0): DMA complete + scS/shS visible

    const int sw = (l15 & 7) << 4;
    const int rb0 = (w * 32 + l15) * 512;
    const int rb1 = rb0 + 16 * 512;
    f32x4 acc0 = {0.f, 0.f, 0.f, 0.f}, acc1 = {0.f, 0.f, 0.f, 0.f};
    #pragma unroll
    for (int kt = 0; kt < 8; ++kt) {
        const int cc = kt * 32 + kg * 8;
        const int xo = (kt * 64 + kg * 16) ^ sw;
        bf16x8 h0  = *(const bf16x8*)(const void*)(hbuf + rb0 + xo);
        bf16x8 h1v = *(const bf16x8*)(const void*)(hbuf + rb1 + xo);
        f32x4 scA = *(const f32x4*)&scS[cc];
        f32x4 scB = *(const f32x4*)&scS[cc + 4];
        f32x4 shA = *(const f32x4*)&shS[cc];
        f32x4 shB = *(const f32x4*)&shS[cc + 4];
        bf16x8 b0, b1;
        #pragma unroll
        for (int e = 0; e < 4; ++e) {
            b0[e]     = (short)f2bf(fmaxf(fmaf(bf2f((unsigned short)h0[e]),      scA[e], shA[e]), 0.f));
            b0[e + 4] = (short)f2bf(fmaxf(fmaf(bf2f((unsigned short)h0[e + 4]),  scB[e], shB[e]), 0.f));
            b1[e]     = (short)f2bf(fmaxf(fmaf(bf2f((unsigned short)h1v[e]),     scA[e], shA[e]), 0.f));
            b1[e + 4] = (short)f2bf(fmaxf(fmaf(bf2f((unsigned short)h1v[e + 4]), scB[e], shB[e]), 0.f));
        }
        acc0 = __builtin_amdgcn_mfma_f32_16x16x32_bf16(af[kt], b0, acc0, 0, 0, 0);
        acc1 = __builtin_amdgcn_mfma_f32_16x16x32_bf16(af[kt], b1, acc1, 0, 0, 0);
    }
    #pragma unroll
    for (int r = 0; r < 4; ++r) {
        LG[(w * 32 + l15) * 17 + kg * 4 + r]      = acc0[r];
        LG[(w * 32 + 16 + l15) * 17 + kg * 4 + r] = acc1[r];
    }
    __syncthreads();

    {   // per-head softmax-weighted gdot
        const int h = t >> 5, j = t & 31;
        float l[4], gv[4];
        #pragma unroll
        for (int q = 0; q < 4; ++q) {
            int n = j + q * 32;
            l[q]  = LG[n * 17 + h];
            gv[q] = LG[n * 17 + 8 + h];
        }
        float m = fmaxf(fmaxf(l[0], l[1]), fmaxf(l[2], l[3]));
        for (int s = 16; s > 0; s >>= 1) m = fmaxf(m, __shfl_xor(m, s, 32));
        float sp = 0.f, sg = 0.f;
        #pragma unroll
        for (int q = 0; q < 4; ++q) {
            float p = expf(l[q] - m);
            sp += p;
            sg = fmaf(p, gv[q], sg);
        }
        for (int s = 16; s > 0; s >>= 1) {
            sp += __shfl_xor(sp, s, 32);
            sg += __shfl_xor(sg, s, 32);
        }
        if (j == 0) redH[h] = sg / sp;
    }
    __syncthreads();
    if (t == 0) {
        float r = c0_g[0];
        #pragma unroll
        for (int h = 0; h < 8; ++h) r += redH[h];
        out[g] = tanhf(r);
    }
}

// ---------------- launch ----------------
// ws: h1 (N*256 u16) | WBg (4096 u16) | floats: psum[256] | psum2[256] | c0[1]
extern "C" void kernel_launch(void* const* d_in, const int* in_sizes, int n_in,
                              void* d_out, int out_size, void* d_ws, size_t ws_size,
                              hipStream_t stream)
{
    (void)in_sizes; (void)n_in; (void)out_size; (void)ws_size;
    const float* x     = (const float*)d_in[0];
    const float* W1    = (const float*)d_in[3];
    // d_in[4] = b1: cancels exactly through the batch-mean subtraction in LN
    const float* gamma = (const float*)d_in[5];
    const float* beta  = (const float*)d_in[6];
    const float* W2    = (const float*)d_in[7];
    const float* b2    = (const float*)d_in[8];
    const float* Wq    = (const float*)d_in[9];
    const float* bq    = (const float*)d_in[10];
    const float* Wk    = (const float*)d_in[11];
    const float* Wv    = (const float*)d_in[13];
    const float* bv    = (const float*)d_in[14];
    const float* Wo    = (const float*)d_in[15];
    const float* bo    = (const float*)d_in[16];
    const float* Wr    = (const float*)d_in[17];
    const float* br    = (const float*)d_in[18];

    unsigned short* h1  = (unsigned short*)d_ws;
    unsigned short* WBg = h1 + (size_t)N_NODES * 256;
    float* fbase = (float*)(WBg + 4096);

    float* psum  = fbase;
    float* psum2 = fbase + 256;
    float* c0    = fbase + 512;

    hipMemsetAsync((void*)psum, 0, 513 * sizeof(float), stream);

    hipLaunchKernelGGL(gemm_kernel, dim3(NFOLD + GEMM_BLOCKS), dim3(256), 0, stream,
                       x, W1, h1, psum, psum2,
                       W2, Wv, b2, bv, bo, Wq, bq, Wk, Wo, Wr, br, WBg, c0);
    hipLaunchKernelGGL(fused_kernel, dim3(B_GRAPHS), dim3(256), 0, stream,
                       h1, psum, psum2, gamma, beta, WBg, c0, (float*)d_out);
}